// Round 6
// baseline (109.865 us; speedup 1.0000x reference)
//
#include <hip/hip_runtime.h>
#include <hip/hip_bf16.h>

// Problem constants (from reference setup_inputs)
#define B_N    4096      // batch
#define D_K    1024      // feature dim
#define MARGIN 0.3f
#define BIGM   1e5f

typedef __attribute__((ext_vector_type(8))) short short8;
typedef __attribute__((ext_vector_type(4))) float f32x4;
typedef __attribute__((ext_vector_type(16))) float f32x16;

__device__ inline ushort f2bf(float f) {
    unsigned u = __float_as_uint(f);
    unsigned r = (u + 0x7fffu + ((u >> 16) & 1u)) >> 16;
    return (ushort)r;
}

__device__ inline void async16(const ushort* g, ushort* l) {
    __builtin_amdgcn_global_load_lds(
        (const __attribute__((address_space(1))) void*)g,
        (__attribute__((address_space(3))) void*)l,
        16, 0, 0);
}

// Fused prep: feat -> bf16 row-major (blocks 0..4095); lut[id] -> bf16 in
// K-tile-PACKED layout Bp[kt][row][64] (blocks 4096..8191) so dist_kernel's
// per-wave register B-loads are line-dense. Also fp32 norms + minmax init.
__global__ void prep_all(const float* __restrict__ feat,
                         const float* __restrict__ lut,
                         const int* __restrict__ id,
                         ushort* __restrict__ featB, ushort* __restrict__ oimP,
                         float* __restrict__ sq_a, float* __restrict__ sq_b,
                         int* __restrict__ maxb, int* __restrict__ minb) {
    int b = blockIdx.x;
    int t = threadIdx.x;                       // 256 threads, 4 floats each
    if (b < 16) {                              // 16*256 = 4096 entries
        int i = b * 256 + t;
        maxb[i] = 0;                           // 0.0f
        minb[i] = 0x7F800000;                  // +inf
    }
    const float* src; float* sq;
    int row;
    bool isA = (b < B_N);
    if (isA) { row = b;        src = feat + (size_t)row * D_K;     sq = sq_a + row; }
    else     { row = b - B_N;  src = lut + (size_t)id[row] * D_K;  sq = sq_b + row; }

    float4 v = ((const float4*)src)[t];
    float ss = v.x * v.x + v.y * v.y + v.z * v.z + v.w * v.w;
    ushort4 bb;
    bb.x = f2bf(v.x); bb.y = f2bf(v.y); bb.z = f2bf(v.z); bb.w = f2bf(v.w);
    if (isA) {
        ((ushort4*)(featB + (size_t)row * D_K))[t] = bb;
    } else {
        // k = t*4..t*4+3 ; kt = t>>4 ; k' = (t&15)*4
        size_t off = (size_t)(t >> 4) * (B_N * 64) + (size_t)row * 64 + (t & 15) * 4;
        *(ushort4*)(oimP + off) = bb;
    }

    int lane = t & 63, w = t >> 6;
    #pragma unroll
    for (int o = 1; o < 64; o <<= 1) ss += __shfl_xor(ss, o);
    __shared__ float red[4];
    if (lane == 0) red[w] = ss;
    __syncthreads();
    if (t == 0) *sq = red[0] + red[1] + red[2] + red[3];
}

// 256x256-tile bf16 GEMM with split operand paths:
//   A: LDS-staged (global_load_lds, XOR chunk swizzle, double-buffered 64 KB)
//   B: per-wave REGISTER loads straight from L2 (packed panels, no LDS,
//      no cross-wave hazard -> no barriers on the B path)
// MFMA 32x32x16 (half the instruction count of 16x16x32).
// 8 waves 2(M)x4(N); per-wave 128x64 = 4x2 tiles of 32x32; BK=64.
// Counted vmcnt(20) (= B(kt):8 + A(kt+1):4 + B(kt+1):8 behind A(kt)'s last).
__global__ __launch_bounds__(512, 2)
void dist_kernel(const ushort* __restrict__ A, const ushort* __restrict__ Bp,
                 const float* __restrict__ sqa, const float* __restrict__ sqb,
                 const int* __restrict__ ids,
                 int* __restrict__ maxb, int* __restrict__ minb) {
    __shared__ ushort lA[2][256 * 64];   // 32 KB x2

    const int t = threadIdx.x;
    const int lane = t & 63;
    const int wid = t >> 6;          // 8 waves
    const int wr = wid >> 2;         // 0..1 (M)
    const int wc = wid & 3;          // 0..3 (N)
    const int l31 = lane & 31;
    const int h2 = lane >> 5;
    const int q7 = l31 & 7;

    // T1 XCD swizzle (256 blocks, bijective)
    const int bid = blockIdx.y * gridDim.x + blockIdx.x;
    const int swz = (bid & 7) * 32 + (bid >> 3);
    const int rb = swz >> 4, cb = swz & 15;

    // ---- A staging: 4 slots of 512thr x 16B cover 256x64. Chunk-XOR src.
    const ushort* gA[4];
    #pragma unroll
    for (int q = 0; q < 4; q++) {
        int elem = q * 4096 + t * 8;
        int r = elem >> 6;
        int j = (elem >> 3) & 7;
        int col = (j ^ (r & 7)) << 3;
        gA[q] = A + (size_t)(rb * 256 + r) * D_K + col;
    }

    // ---- B register-load base pointers (kt=0), packed rows of 64
    const ushort* gB[2][4];
    #pragma unroll
    for (int nt = 0; nt < 2; nt++) {
        int row = cb * 256 + wc * 64 + nt * 32 + l31;
        #pragma unroll
        for (int ks = 0; ks < 4; ks++)
            gB[nt][ks] = Bp + (size_t)row * 64 + ks * 16 + h2 * 8;
    }

    f32x16 acc[4][2] = {};
    short8 b0[2][4], b1[2][4];

#define STAGE_A(ktv, sw)                                                   \
    _Pragma("unroll") for (int q = 0; q < 4; q++)                          \
        async16(gA[q] + (ktv) * 64, &lA[sw][q * 4096 + wid * 512]);

#define LOAD_B(dst, ktv)                                                   \
    _Pragma("unroll") for (int nt = 0; nt < 2; nt++)                       \
    _Pragma("unroll") for (int ks = 0; ks < 4; ks++)                       \
        dst[nt][ks] = *(const short8*)(gB[nt][ks] + (size_t)(ktv) * (B_N * 64));

#define BODY(sr, bset)                                                     \
    _Pragma("unroll") for (int mt = 0; mt < 4; mt++) {                     \
        short8 af[4];                                                      \
        const ushort* rowp = &lA[sr][(wr * 128 + mt * 32 + l31) * 64];     \
        _Pragma("unroll") for (int ks = 0; ks < 4; ks++)                   \
            af[ks] = *(const short8*)(rowp + (((ks * 2 + h2) ^ q7) << 3)); \
        _Pragma("unroll") for (int nt = 0; nt < 2; nt++)                   \
        _Pragma("unroll") for (int ks = 0; ks < 4; ks++)                   \
            acc[mt][nt] = __builtin_amdgcn_mfma_f32_32x32x16_bf16(         \
                af[ks], bset[nt][ks], acc[mt][nt], 0, 0, 0);               \
    }

    // prologue: K-tile 0
    STAGE_A(0, 0);
    LOAD_B(b0, 0);

    for (int kt = 0; kt < 16; kt += 2) {
        // -------- even kt: compute lA[0]/b0, prefetch kt+1 --------
        STAGE_A(kt + 1, 1);
        LOAD_B(b1, kt + 1);
        asm volatile("s_waitcnt vmcnt(20)" ::: "memory");  // A(kt) landed
        __builtin_amdgcn_sched_barrier(0);
        __builtin_amdgcn_s_barrier();                      // RAW: lA[0] visible
        __builtin_amdgcn_s_setprio(1);
        BODY(0, b0);
        __builtin_amdgcn_s_setprio(0);
        __builtin_amdgcn_sched_barrier(0);
        __builtin_amdgcn_s_barrier();                      // WAR: lA[0] reads done

        // -------- odd kt+1: compute lA[1]/b1, prefetch kt+2 --------
        if (kt + 2 < 16) {
            STAGE_A(kt + 2, 0);
            LOAD_B(b0, kt + 2);
            asm volatile("s_waitcnt vmcnt(20)" ::: "memory");  // A(kt+1) landed
        } else {
            asm volatile("s_waitcnt vmcnt(8)" ::: "memory");
        }
        __builtin_amdgcn_sched_barrier(0);
        __builtin_amdgcn_s_barrier();                      // RAW: lA[1] visible
        __builtin_amdgcn_s_setprio(1);
        BODY(1, b1);
        __builtin_amdgcn_s_setprio(0);
        __builtin_amdgcn_sched_barrier(0);
        __builtin_amdgcn_s_barrier();                      // WAR: lA[1] reads done
    }
#undef STAGE_A
#undef LOAD_B
#undef BODY

    // Epilogue: dist + masks + per-row max/min over this block's 256 cols.
    // 32x32 C/D mapping: col = lane&31, row = (r&3) + 8*(r>>2) + 4*(lane>>5).
    int colg[2]; float sb[2]; int idb[2];
    #pragma unroll
    for (int nt = 0; nt < 2; nt++) {
        int c = cb * 256 + wc * 64 + nt * 32 + l31;
        colg[nt] = c; sb[nt] = sqb[c]; idb[nt] = ids[c];
    }
    #pragma unroll
    for (int mt = 0; mt < 4; mt++) {
        #pragma unroll
        for (int r = 0; r < 16; r++) {
            int lrow = (r & 3) + 8 * (r >> 2) + 4 * h2;
            int row = rb * 256 + wr * 128 + mt * 32 + lrow;
            float sa = sqa[row];
            int ida = ids[row];
            float mx = 0.0f, mn = 3.0e38f;
            #pragma unroll
            for (int nt = 0; nt < 2; nt++) {
                float s2 = sa + sb[nt] - 2.0f * acc[mt][nt][r];
                float d = sqrtf(fmaxf(s2, 0.0f) + 1e-12f);
                bool same = (ida == idb[nt]);
                float pv = (same && (row != colg[nt])) ? d : 0.0f;
                float nv = same ? d + BIGM : d;
                mx = fmaxf(mx, pv);
                mn = fminf(mn, nv);
            }
            #pragma unroll
            for (int o = 1; o < 32; o <<= 1) {   // reduce across 32-lane half
                mx = fmaxf(mx, __shfl_xor(mx, o));
                mn = fminf(mn, __shfl_xor(mn, o));
            }
            if (l31 == 0) {
                atomicMax(maxb + row, __float_as_int(mx));
                atomicMin(minb + row, __float_as_int(mn));
            }
        }
    }
}

__global__ void finalize_k(const int* __restrict__ maxb, const int* __restrict__ minb,
                           float* __restrict__ out) {
    int i = blockIdx.x * blockDim.x + threadIdx.x;
    if (i < B_N) {
        float z = __int_as_float(maxb[i]) - __int_as_float(minb[i]) + MARGIN;
        out[i] = fmaxf(z, 0.0f);
    }
}

extern "C" void kernel_launch(void* const* d_in, const int* in_sizes, int n_in,
                              void* d_out, int out_size, void* d_ws, size_t ws_size,
                              hipStream_t stream) {
    const float* feat = (const float*)d_in[0];
    const float* lut  = (const float*)d_in[1];
    const int*   id   = (const int*)d_in[2];
    float* out = (float*)d_out;

    // workspace layout
    char* ws = (char*)d_ws;
    ushort* featB = (ushort*)ws;                                  // 8 MiB
    ushort* oimP  = (ushort*)(ws + (size_t)B_N * D_K * 2);        // 8 MiB (packed)
    float*  sq_a  = (float*)(ws + (size_t)2 * B_N * D_K * 2);
    float*  sq_b  = sq_a + B_N;
    int*    maxb  = (int*)(sq_b + B_N);
    int*    minb  = maxb + B_N;

    prep_all<<<2 * B_N, 256, 0, stream>>>(feat, lut, id, featB, oimP,
                                          sq_a, sq_b, maxb, minb);

    dim3 grid(B_N / 256, B_N / 256);
    dist_kernel<<<grid, 512, 0, stream>>>(featB, oimP, sq_a, sq_b, id, maxb, minb);

    finalize_k<<<(B_N + 255) / 256, 256, 0, stream>>>(maxb, minb, out);
}

// Round 7
// 65.701 us; speedup vs baseline: 1.6722x; 1.6722x over previous
//
#include <hip/hip_runtime.h>
#include <hip/hip_bf16.h>

// Problem constants (from reference setup_inputs)
#define B_N    4096      // batch
#define D_K    1024      // feature dim
#define MARGIN 0.3f
#define BIGM   1e5f

typedef __attribute__((ext_vector_type(8))) short short8;
typedef __attribute__((ext_vector_type(4))) float f32x4;

__device__ inline ushort f2bf(float f) {
    unsigned u = __float_as_uint(f);
    unsigned r = (u + 0x7fffu + ((u >> 16) & 1u)) >> 16;
    return (ushort)r;
}

__device__ inline void async16(const ushort* g, ushort* l) {
    __builtin_amdgcn_global_load_lds(
        (const __attribute__((address_space(1))) void*)g,
        (__attribute__((address_space(3))) void*)l,
        16, 0, 0);
}

// Fused prep: convert feat -> bf16 (blocks 0..4095) and lut[id] -> bf16
// (blocks 4096..8191), compute fp32 squared row norms, and init min/max bufs.
__global__ void prep_all(const float* __restrict__ feat,
                         const float* __restrict__ lut,
                         const int* __restrict__ id,
                         ushort* __restrict__ featB, ushort* __restrict__ oimB,
                         float* __restrict__ sq_a, float* __restrict__ sq_b,
                         int* __restrict__ maxb, int* __restrict__ minb) {
    int b = blockIdx.x;
    int t = threadIdx.x;                       // 256 threads, 4 floats each
    if (b < 16) {                              // 16*256 = 4096 entries
        int i = b * 256 + t;
        maxb[i] = 0;                           // 0.0f
        minb[i] = 0x7F800000;                  // +inf
    }
    const float* src; ushort* dst; float* sq;
    if (b < B_N) {
        src = feat + (size_t)b * D_K;
        dst = featB + (size_t)b * D_K;
        sq  = sq_a + b;
    } else {
        int row = b - B_N;
        src = lut + (size_t)id[row] * D_K;
        dst = oimB + (size_t)row * D_K;
        sq  = sq_b + row;
    }
    float4 v = ((const float4*)src)[t];
    float ss = v.x * v.x + v.y * v.y + v.z * v.z + v.w * v.w;
    ushort4 bb;
    bb.x = f2bf(v.x); bb.y = f2bf(v.y); bb.z = f2bf(v.z); bb.w = f2bf(v.w);
    ((ushort4*)dst)[t] = bb;

    int lane = t & 63, w = t >> 6;
    #pragma unroll
    for (int o = 1; o < 64; o <<= 1) ss += __shfl_xor(ss, o);
    __shared__ float red[4];
    if (lane == 0) red[w] = ss;
    __syncthreads();
    if (t == 0) *sq = red[0] + red[1] + red[2] + red[3];
}

// 256x256-tile bf16 MFMA GEMM.
//   BK=32, TRIPLE-buffered LDS (96 KiB): staging lead = 2 K-tiles >> latency,
//   counted vmcnt(4) at every tile top (exact: 4 newest = next tile's loads),
//   2 paced phases/tile (Q0=mf0-3, Q1=mf4-7); Q1 reads + B-stage issued in
//   Q0's MFMA shadow (latency hidden under barrier B2).
//   Row-pair XOR swizzle: logical (r, j16B) stored at line (r>>1)*128B,
//   slot = (((r&1)<<2)|j) ^ ((r>>1)&7)  -> every 16-lane b128 pass covers
//   all 8 slot-groups (2 lanes each = free 2-way).
// 8 waves 2(M)x4(N); per-wave 128x64 via 8x4 frags of 16x16x32.
__global__ __launch_bounds__(512, 2)
void dist_kernel(const ushort* __restrict__ A, const ushort* __restrict__ Bm,
                 const float* __restrict__ sqa, const float* __restrict__ sqb,
                 const int* __restrict__ ids,
                 int* __restrict__ maxb, int* __restrict__ minb) {
    __shared__ ushort lds_[3 * 16384];   // 3 bufs x (A 8192 + B 8192) elems

    const int t = threadIdx.x;
    const int lane = t & 63;
    const int wid = t >> 6;          // 8 waves
    const int wr = wid >> 2;         // 0..1 (M)
    const int wc = wid & 3;          // 0..3 (N)
    const int l15 = lane & 15;
    const int h = lane >> 4;

    // T1 XCD swizzle (256 blocks, bijective)
    const int bid = blockIdx.y * gridDim.x + blockIdx.x;
    const int swz = (bid & 7) * 32 + (bid >> 3);
    const int rb = swz >> 4, cb = swz & 15;

    // ---- staging sources: 2 instrs per operand per tile (512thr x 16B).
    // Linear phys elem p = q*4096 + t*8; line rp=p>>6, slot'=(p>>3)&7;
    // logical slot = slot' ^ (rp&7); r = rp*2 + (slot>>2); j = slot&3.
    const ushort* gsrc[2][2];        // [op A/B][q]
    #pragma unroll
    for (int q = 0; q < 2; q++) {
        int p = q * 4096 + t * 8;
        int rp = p >> 6;
        int sl = ((p >> 3) & 7) ^ (rp & 7);
        int r = rp * 2 + (sl >> 2);
        int j = sl & 3;
        gsrc[0][q] = A  + (size_t)(rb * 256 + r) * D_K + j * 8;
        gsrc[1][q] = Bm + (size_t)(cb * 256 + r) * D_K + j * 8;
    }
    const int lds_wo = wid * 512;    // wave-uniform lane-block offset (elems)

    // ---- swizzled fragment read offsets (elements within an 8192 buffer)
    int offA[8], offB[4];
    {
        int par = (l15 & 1) << 2;
        int a0 = (wr * 128 + l15) >> 1;
        #pragma unroll
        for (int mf = 0; mf < 8; mf++) {
            int line = a0 + mf * 8;
            offA[mf] = line * 64 + (((par | h) ^ (line & 7)) << 3);
        }
        int b0 = (wc * 64 + l15) >> 1;
        #pragma unroll
        for (int nf = 0; nf < 4; nf++) {
            int line = b0 + nf * 8;
            offB[nf] = line * 64 + (((par | h) ^ (line & 7)) << 3);
        }
    }

    f32x4 acc[8][4] = {};

    // ---- prologue: stage tiles 0 and 1 into bufs 0 and 1
    #pragma unroll
    for (int kt0 = 0; kt0 < 2; kt0++) {
        ushort* base = lds_ + kt0 * 16384;
        async16(gsrc[0][0] + kt0 * 32, base + lds_wo);
        async16(gsrc[0][1] + kt0 * 32, base + 4096 + lds_wo);
        async16(gsrc[1][0] + kt0 * 32, base + 8192 + lds_wo);
        async16(gsrc[1][1] + kt0 * 32, base + 12288 + lds_wo);
    }

    int s3 = 0, w3 = 2;
    for (int kt = 0; kt < 32; ++kt) {
        const ushort* sA = lds_ + s3 * 16384;
        const ushort* sB = sA + 8192;
        ushort* wA = lds_ + w3 * 16384;
        ushort* wB = wA + 8192;
        const int nc = (kt + 2) * 32;
        const bool more = (kt <= 29);

        // B1: tile kt resident (vmcnt: this wave's DMAs; barrier: all waves)
        if (kt < 31) asm volatile("s_waitcnt vmcnt(4)" ::: "memory");
        else         asm volatile("s_waitcnt vmcnt(0)" ::: "memory");
        __builtin_amdgcn_sched_barrier(0);
        __builtin_amdgcn_s_barrier();
        __builtin_amdgcn_sched_barrier(0);

        short8 afv[8], bfv[4];
        #pragma unroll
        for (int mf = 0; mf < 4; mf++)
            afv[mf] = *(const short8*)(sA + offA[mf]);
        #pragma unroll
        for (int nf = 0; nf < 4; nf++)
            bfv[nf] = *(const short8*)(sB + offB[nf]);
        if (more) {
            async16(gsrc[0][0] + nc, wA + lds_wo);
            async16(gsrc[0][1] + nc, wA + 4096 + lds_wo);
        }
        asm volatile("s_waitcnt lgkmcnt(0)" ::: "memory");
        __builtin_amdgcn_sched_barrier(0);
        __builtin_amdgcn_s_setprio(1);
        #pragma unroll
        for (int mf = 0; mf < 4; mf++)
            #pragma unroll
            for (int nf = 0; nf < 4; nf++)
                acc[mf][nf] = __builtin_amdgcn_mfma_f32_16x16x32_bf16(
                    afv[mf], bfv[nf], acc[mf][nf], 0, 0, 0);
        __builtin_amdgcn_s_setprio(0);

        // Q1 reads + B-stage in Q0's shadow (hidden under B2)
        #pragma unroll
        for (int mf = 4; mf < 8; mf++)
            afv[mf] = *(const short8*)(sA + offA[mf]);
        if (more) {
            async16(gsrc[1][0] + nc, wB + lds_wo);
            async16(gsrc[1][1] + nc, wB + 4096 + lds_wo);
        }
        __builtin_amdgcn_sched_barrier(0);
        __builtin_amdgcn_s_barrier();    // B2: phase pacing
        asm volatile("s_waitcnt lgkmcnt(0)" ::: "memory");
        __builtin_amdgcn_sched_barrier(0);
        __builtin_amdgcn_s_setprio(1);
        #pragma unroll
        for (int mf = 4; mf < 8; mf++)
            #pragma unroll
            for (int nf = 0; nf < 4; nf++)
                acc[mf][nf] = __builtin_amdgcn_mfma_f32_16x16x32_bf16(
                    afv[mf], bfv[nf], acc[mf][nf], 0, 0, 0);
        __builtin_amdgcn_s_setprio(0);
        __builtin_amdgcn_sched_barrier(0);

        s3 = (s3 == 2) ? 0 : s3 + 1;
        w3 = (w3 == 2) ? 0 : w3 + 1;
    }

    // Epilogue: dist + masks + per-row max/min over this block's 256 cols.
    int colg[4]; float sb[4]; int idb[4];
    #pragma unroll
    for (int n = 0; n < 4; n++) {
        int c = cb * 256 + wc * 64 + n * 16 + l15;
        colg[n] = c; sb[n] = sqb[c]; idb[n] = ids[c];
    }
    #pragma unroll
    for (int m = 0; m < 8; m++) {
        #pragma unroll
        for (int r = 0; r < 4; r++) {
            int row = rb * 256 + wr * 128 + m * 16 + h * 4 + r;
            float sa = sqa[row];
            int ida = ids[row];
            float mx = 0.0f, mn = 3.0e38f;
            #pragma unroll
            for (int n = 0; n < 4; n++) {
                float s2 = sa + sb[n] - 2.0f * acc[m][n][r];
                float d = sqrtf(fmaxf(s2, 0.0f) + 1e-12f);
                bool same = (ida == idb[n]);
                float pv = (same && (row != colg[n])) ? d : 0.0f;
                float nv = same ? d + BIGM : d;
                mx = fmaxf(mx, pv);
                mn = fminf(mn, nv);
            }
            #pragma unroll
            for (int o = 1; o < 16; o <<= 1) {
                mx = fmaxf(mx, __shfl_xor(mx, o));
                mn = fminf(mn, __shfl_xor(mn, o));
            }
            if (l15 == 0) {
                atomicMax(maxb + row, __float_as_int(mx));
                atomicMin(minb + row, __float_as_int(mn));
            }
        }
    }
}

__global__ void finalize_k(const int* __restrict__ maxb, const int* __restrict__ minb,
                           float* __restrict__ out) {
    int i = blockIdx.x * blockDim.x + threadIdx.x;
    if (i < B_N) {
        float z = __int_as_float(maxb[i]) - __int_as_float(minb[i]) + MARGIN;
        out[i] = fmaxf(z, 0.0f);
    }
}

extern "C" void kernel_launch(void* const* d_in, const int* in_sizes, int n_in,
                              void* d_out, int out_size, void* d_ws, size_t ws_size,
                              hipStream_t stream) {
    const float* feat = (const float*)d_in[0];
    const float* lut  = (const float*)d_in[1];
    const int*   id   = (const int*)d_in[2];
    float* out = (float*)d_out;

    // workspace layout
    char* ws = (char*)d_ws;
    ushort* featB = (ushort*)ws;                                  // 8 MiB
    ushort* oimB  = (ushort*)(ws + (size_t)B_N * D_K * 2);        // 8 MiB
    float*  sq_a  = (float*)(ws + (size_t)2 * B_N * D_K * 2);
    float*  sq_b  = sq_a + B_N;
    int*    maxb  = (int*)(sq_b + B_N);
    int*    minb  = maxb + B_N;

    prep_all<<<2 * B_N, 256, 0, stream>>>(feat, lut, id, featB, oimB,
                                          sq_a, sq_b, maxb, minb);

    dim3 grid(B_N / 256, B_N / 256);
    dist_kernel<<<grid, 512, 0, stream>>>(featB, oimB, sq_a, sq_b, id, maxb, minb);

    finalize_k<<<(B_N + 255) / 256, 256, 0, stream>>>(maxb, minb, out);
}